// Round 1
// baseline (188.319 us; speedup 1.0000x reference)
//
#include <hip/hip_runtime.h>
#include <math.h>

// x: (B, 63, 16) fp32, row = 1008 floats = 4032 B contiguous; out: (B, 21) fp32.
// One wave (64 lanes) per row. The row is loaded COALESCED: 252 float4s split
// across 64 lanes x 4 iterations (1024 contiguous bytes per wave instruction).
// Needed channels are scattered into a small per-wave LDS slice, then the
// original shuffle-scan statistics pipeline runs unchanged.
//
// float4 #m of the row covers floats 4m..4m+3:
//   m % 4 == 0 -> .x = r[m/4]            (channel 0)
//   m % 4 == 2 -> .z = volf[(m-2)/4]     (channel 10)
//   m == 248   -> .y = rsi[62]           (float 993)
//   m == 251   -> .w = momf[62]          (float 1007)

__device__ __forceinline__ float wsum(float v) {
    #pragma unroll
    for (int d = 32; d > 0; d >>= 1) v += __shfl_xor(v, d, 64);
    return v;
}
__device__ __forceinline__ float wmax(float v) {
    #pragma unroll
    for (int d = 32; d > 0; d >>= 1) v = fmaxf(v, __shfl_xor(v, d, 64));
    return v;
}
__device__ __forceinline__ float wmin(float v) {
    #pragma unroll
    for (int d = 32; d > 0; d >>= 1) v = fminf(v, __shfl_xor(v, d, 64));
    return v;
}

__global__ __launch_bounds__(256) void regime_kernel(const float* __restrict__ x,
                                                     float* __restrict__ out,
                                                     int B) {
    __shared__ float s_r[4][64];     // r[0..62] per wave
    __shared__ float s_vf[4][21];    // volf[42..62] per wave
    __shared__ float s_misc[4][2];   // rsi62, momf62 per wave

    const int wave = threadIdx.x >> 6;
    const int lane = threadIdx.x & 63;
    const int row  = blockIdx.x * 4 + wave;
    if (row >= B) return;

    const float* xr = x + (size_t)row * (63 * 16);

    // ---- coalesced row load: float4 #(lane + 64k), k=0..3 (252 total) ----
    float4 v0 = *(const float4*)(xr + (size_t)lane * 4);
    float4 v1 = *(const float4*)(xr + (size_t)(lane + 64) * 4);
    float4 v2 = *(const float4*)(xr + (size_t)(lane + 128) * 4);
    float4 v3 = make_float4(0.f, 0.f, 0.f, 0.f);
    if (lane < 60) v3 = *(const float4*)(xr + (size_t)(lane + 192) * 4);

    // ---- scatter needed channels into this wave's LDS slice ----
    const int rem = lane & 3;
    if (rem == 0) {
        // m%4==0 -> r[m>>2]; 16 lanes write 16 distinct banks (conflict-free)
        s_r[wave][(lane)       >> 2] = v0.x;   // t = 0..15
        s_r[wave][(lane + 64)  >> 2] = v1.x;   // t = 16..31
        s_r[wave][(lane + 128) >> 2] = v2.x;   // t = 32..47
        if (lane < 60) s_r[wave][(lane + 192) >> 2] = v3.x;  // t = 48..62
    } else if (rem == 2) {
        // m%4==2 -> volf[m>>2]; only t>=42 needed
        {
            const int t = (lane + 128) >> 2;   // t = 32..47
            if (t >= 42) s_vf[wave][t - 42] = v2.z;
        }
        if (lane < 60) {
            const int t = (lane + 192) >> 2;   // t = 48..62, all >= 42
            s_vf[wave][t - 42] = v3.z;
        }
    }
    if (lane == 56) s_misc[wave][0] = v3.y;    // m=248: rsi[62]
    if (lane == 59) s_misc[wave][1] = v3.w;    // m=251: momf[62]

    // Same wave wrote and reads its own slice; DS ops are in-order per wave,
    // the compiler inserts the lgkmcnt waits. No barrier needed.

    // ---- gather per-lane values ----
    const float rt = (lane < 63) ? s_r[wave][lane] : 0.f;                      // r[lane]
    const float vf = (lane >= 42 && lane < 63) ? s_vf[wave][lane - 42] : 0.f;  // volf[lane]

    const float r2 = rt * rt;

    // ---- inclusive prefix scans over lanes: r, r^2, |r|, r^3 ----
    float pr = rt, pq = r2, pa = fabsf(rt), pc = r2 * rt;
    #pragma unroll
    for (int d = 1; d < 64; d <<= 1) {
        float a = __shfl_up(pr, d, 64);
        float b = __shfl_up(pq, d, 64);
        float c = __shfl_up(pa, d, 64);
        float e = __shfl_up(pc, d, 64);
        if (lane >= d) { pr += a; pq += b; pa += c; pc += e; }
    }

    const float S  = __shfl(pr, 62, 64);  // sum r
    const float Q  = __shfl(pq, 62, 64);  // sum r^2
    const float SA = __shfl(pa, 62, 64);  // sum |r|
    const float SC = __shfl(pc, 62, 64);  // sum r^3

    const float mx = wmax(lane < 63 ? rt : -INFINITY);
    const float mn = wmin(lane < 63 ? rt :  INFINITY);

    // lag-1 product sum over t=0..61
    const float rnext = __shfl_down(rt, 1, 64);
    const float SL = wsum((lane < 62) ? rt * rnext : 0.f);

    // volf sum over steps 42..62
    const float SV = wsum(vf);

    // ---- vol_long (ddof=1, n=63) ----
    float varL = (Q - S * S / 63.f) / 62.f;
    const float vol_long = sqrtf(fmaxf(varL, 0.f));

    // ---- vol_short: window [42..62], n=21, ddof=1 ----
    const float P41r = __shfl(pr, 41, 64);
    const float P41q = __shfl(pq, 41, 64);
    const float Ss = S - P41r, Qs = Q - P41q;
    const float vol_short = sqrtf(fmaxf((Qs - Ss * Ss / 21.f) / 20.f, 0.f));

    // ---- 9 sliding windows j=62,57,...,22; window [j-21..j], n=22, ddof=1 ----
    const int k = (lane < 9) ? lane : 0;
    const int j = 62 - 5 * k;
    const float Wr = __shfl(pr, j, 64) - __shfl(pr, j - 22, 64);
    const float Wq = __shfl(pq, j, 64) - __shfl(pq, j - 22, 64);
    const float vsk = sqrtf(fmaxf((Wq - Wr * Wr / 22.f) / 21.f, 0.f));
    const float vsum = wsum(lane < 9 ? vsk : 0.f);
    const float vsqs = wsum(lane < 9 ? vsk * vsk : 0.f);
    const float vs0 = __shfl(vsk, 0, 64);
    const float vs8 = __shfl(vsk, 8, 64);
    const float vmean = vsum / 9.f;
    const float vol_persistence = sqrtf(fmaxf(vsqs / 9.f - vmean * vmean, 0.f));  // ddof=0
    const float vol_trend = vs0 - vs8;

    // ---- lag-1 autocorr over (r[0..61], r[1..62]) ----
    const float r0  = __shfl(rt, 0, 64);
    const float r62 = __shfl(rt, 62, 64);
    const float r42 = __shfl(rt, 42, 64);
    const float Sa = S - r62, Sb = S - r0;
    const float Qa = Q - r62 * r62, Qb = Q - r0 * r0;
    const float num = SL - Sa * Sb / 62.f;
    const float va = Qa - Sa * Sa / 62.f;
    const float vb = Qb - Sb * Sb / 62.f;
    const float corr = num / sqrtf(va * vb);
    const float trend = (corr != corr) ? 0.5f : fabsf(corr);  // NaN -> 0.5

    // ---- remaining scalars ----
    const float mean_returns = S / 63.f;
    const float abs_mean = SA / 63.f;
    const float range = mx - mn;
    float skew = 0.f;
    if (vol_long >= 1e-8f) {
        const float mu = mean_returns;
        const float cs = SC - 3.f * mu * Q + 2.f * 63.f * mu * mu * mu;  // sum (r-mu)^3
        skew = cs / (63.f * vol_long * vol_long * vol_long);
    }
    const float momentum_short = r62 / (r42 + 1e-8f) - 1.f;
    const float rsi_c  = s_misc[wave][0];
    const float momf_c = s_misc[wave][1];
    const float vol_ratio = vol_short / (vol_long + 1e-8f);
    const float high_vol = (vol_short > 0.03f) ? 1.f : 0.f;
    const float med_vol  = (vol_short >= 0.01f && vol_short <= 0.03f) ? 1.f : 0.f;
    const float low_vol  = (vol_short < 0.01f) ? 1.f : 0.f;
    const float vol_feature_mean = SV / 21.f;

    // ---- write 21 features, lane f writes feature f ----
    if (lane < 21) {
        float f;
        switch (lane) {
            case 0:  f = high_vol; break;
            case 1:  f = med_vol; break;
            case 2:  f = low_vol; break;
            case 3:  f = trend; break;
            case 4:  f = vol_ratio; break;
            case 5:  f = mean_returns; break;
            case 6:  f = abs_mean; break;
            case 7:  f = range; break;
            case 8:  f = skew; break;
            case 9:  f = momentum_short; break;
            case 10: f = rsi_c; break;
            case 11: f = vol_feature_mean; break;
            case 12: f = momf_c; break;
            case 13: f = 0.f;   break;  // relative_return
            case 14: f = 1.f;   break;  // relative_vol
            case 15: f = 1.f;   break;  // beta
            case 16: f = 0.f;   break;  // relative_strength
            case 17: f = 0.02f; break;  // market_vol_level
            case 18: f = vol_persistence; break;
            case 19: f = vol_trend; break;
            default: f = 0.f;   break;  // regime_shift
        }
        out[(size_t)row * 21 + lane] = f;
    }
}

extern "C" void kernel_launch(void* const* d_in, const int* in_sizes, int n_in,
                              void* d_out, int out_size, void* d_ws, size_t ws_size,
                              hipStream_t stream) {
    const float* x = (const float*)d_in[0];
    float* out = (float*)d_out;
    const int B = in_sizes[0] / (63 * 16);
    const int blocks = (B + 3) / 4;  // 4 waves per block, one row per wave
    regime_kernel<<<blocks, 256, 0, stream>>>(x, out, B);
}

// Round 2
// 187.879 us; speedup vs baseline: 1.0023x; 1.0023x over previous
//
#include <hip/hip_runtime.h>
#include <math.h>

// x: (B, 63, 16) fp32; out: (B, 21) fp32.
// 16 lanes per row, 4 rows per wave, 4 waves per block (16 rows/block).
// Each lane holds 4 timesteps (t = 4*li .. 4*li+3) of channel 0 (r) and
// channel 10 (volf) in registers. All statistics via group-local (16-lane)
// scans/reductions -> every wave-wide DS instruction serves 4 rows, cutting
// DS-pipe pressure ~5x vs the one-row-per-wave version (which was DS-bound
// at ~27 us vs the 21 us HBM fetch floor for the 132 MB input).
//
// Prefix sums at arbitrary index j are reconstructed lane-parallel as
//   P(j) = Scan(j>>2) - trailing(j&3)   via ds_bpermute gathers.

__global__ __launch_bounds__(256) void regime_kernel(const float* __restrict__ x,
                                                     float* __restrict__ out,
                                                     int B) {
    const int lane = threadIdx.x & 63;
    const int li   = lane & 15;   // lane within row-group
    const int go   = lane & 48;   // group base lane within wave (0,16,32,48)
    const int row  = blockIdx.x * 16 + (threadIdx.x >> 4);
    if (row >= B) return;

    const float* xr = x + (size_t)row * (63 * 16);
    const int t0 = li * 4;

    // ---- per-lane loads: 4 timesteps of r (ch 0) and volf (ch 10) ----
    const float e0 = xr[(t0 + 0) * 16];
    const float e1 = xr[(t0 + 1) * 16];
    const float e2 = xr[(t0 + 2) * 16];
    float e3 = 0.f, v3 = 0.f;
    const float v0 = xr[(t0 + 0) * 16 + 10];
    const float v1 = xr[(t0 + 1) * 16 + 10];
    const float v2 = xr[(t0 + 2) * 16 + 10];
    if (li < 15) {                       // t=63 doesn't exist for li==15
        e3 = xr[(t0 + 3) * 16];
        v3 = xr[(t0 + 3) * 16 + 10];
    }
    // scalars at t=62 (same cache line as r[62]; uniform per group)
    const float rsi_c  = xr[62 * 16 + 1];
    const float momf_c = xr[62 * 16 + 15];

    // ---- per-lane locals (VALU only) ----
    const float q0 = e0 * e0, q1 = e1 * e1, q2 = e2 * e2, q3 = e3 * e3;
    const float l4r = (e0 + e1) + (e2 + e3);
    const float l4q = (q0 + q1) + (q2 + q3);
    const float la  = (fabsf(e0) + fabsf(e1)) + (fabsf(e2) + fabsf(e3));
    const float lc  = (q0 * e0 + q1 * e1) + (q2 * e2 + q3 * e3);
    float me = fmaxf(fmaxf(e0, e1), e2);
    float mi = fminf(fminf(e0, e1), e2);
    if (li < 15) { me = fmaxf(me, e3); mi = fminf(mi, e3); }
    // lag-1 products: in-lane pairs + boundary pair e3*next.e0
    float sl = e0 * e1 + e1 * e2 + e2 * e3;
    const float nx = __shfl_down(e0, 1, 64);   // cross-group reads masked by e3==0
    sl += e3 * nx;
    // volf sum over t>=42: li==10 -> t=42,43 only; li>=11 -> all (v3=0 pads li==15)
    const float svl = (li > 10) ? ((v0 + v1) + (v2 + v3))
                    : (li == 10) ? (v2 + v3) : 0.f;
    // trailing sums for prefix reconstruction: trail(s)= sum of elems after pos s
    const float t1r = e3, t2r = e2 + e3, t3r = e1 + t2r;
    const float t1q = q3, t2q = q2 + q3, t3q = q1 + t2q;

    // ---- group-inclusive scans of (l4r, l4q): 4 steps ----
    float sr = l4r, sq = l4q;
    #pragma unroll
    for (int d = 1; d < 16; d <<= 1) {
        const float ur = __shfl_up(sr, d, 64);
        const float uq = __shfl_up(sq, d, 64);
        if (li >= d) { sr += ur; sq += uq; }
    }
    // sr/sq at lane li = sum over t <= 4*li+3 (r[63]:=0)

    // ---- group butterflies (xor 8,4,2,1 stays within 16-lane group) ----
    float SA = la, SC = lc, MX = me, MN = mi, SL = sl, SV = svl;
    #pragma unroll
    for (int d = 8; d > 0; d >>= 1) {
        SA += __shfl_xor(SA, d, 64);
        SC += __shfl_xor(SC, d, 64);
        MX  = fmaxf(MX, __shfl_xor(MX, d, 64));
        MN  = fminf(MN, __shfl_xor(MN, d, 64));
        SL += __shfl_xor(SL, d, 64);
        SV += __shfl_xor(SV, d, 64);
    }

    // ---- windows: lane k<=8 handles window j=62-5k; lane 9 handles P(41) ----
    const int lk = (li <= 9) ? li : 0;
    const int jU = (lk == 9) ? 41 : 62 - 5 * lk;
    const int jL = (lk == 9) ? 3  : 40 - 5 * lk;
    const int mU = go + (jU >> 2), sU = jU & 3;
    const int mL = go + (jL >> 2), sL_ = jL & 3;

    // gather P(j) = Scan(m) - trail(s)  (4 bpermutes per endpoint per array)
    float PUr, PUq, PLr, PLq;
    {
        const float Su = __shfl(sr, mU, 64);
        const float a1 = __shfl(t1r, mU, 64);
        const float a2 = __shfl(t2r, mU, 64);
        const float a3 = __shfl(t3r, mU, 64);
        const float tr = (sU == 3) ? 0.f : (sU == 2) ? a1 : (sU == 1) ? a2 : a3;
        PUr = Su - tr;
    }
    {
        const float Su = __shfl(sq, mU, 64);
        const float a1 = __shfl(t1q, mU, 64);
        const float a2 = __shfl(t2q, mU, 64);
        const float a3 = __shfl(t3q, mU, 64);
        const float tr = (sU == 3) ? 0.f : (sU == 2) ? a1 : (sU == 1) ? a2 : a3;
        PUq = Su - tr;
    }
    {
        const float Su = __shfl(sr, mL, 64);
        const float a1 = __shfl(t1r, mL, 64);
        const float a2 = __shfl(t2r, mL, 64);
        const float a3 = __shfl(t3r, mL, 64);
        const float tr = (sL_ == 3) ? 0.f : (sL_ == 2) ? a1 : (sL_ == 1) ? a2 : a3;
        PLr = Su - tr;
    }
    {
        const float Su = __shfl(sq, mL, 64);
        const float a1 = __shfl(t1q, mL, 64);
        const float a2 = __shfl(t2q, mL, 64);
        const float a3 = __shfl(t3q, mL, 64);
        const float tr = (sL_ == 3) ? 0.f : (sL_ == 2) ? a1 : (sL_ == 1) ? a2 : a3;
        PLq = Su - tr;
    }

    const float Wr = PUr - PLr, Wq = PUq - PLq;
    const float vsk = sqrtf(fmaxf((Wq - Wr * Wr / 22.f) / 21.f, 0.f));

    // reduce window stats over lanes 0..8 of the group
    float vsum = (li <= 8) ? vsk : 0.f;
    float vsqs = (li <= 8) ? vsk * vsk : 0.f;
    #pragma unroll
    for (int d = 8; d > 0; d >>= 1) {
        vsum += __shfl_xor(vsum, d, 64);
        vsqs += __shfl_xor(vsqs, d, 64);
    }

    // ---- broadcasts ----
    const float S    = __shfl(sr, go + 15, 64);
    const float Q    = __shfl(sq, go + 15, 64);
    const float P41r = __shfl(PUr, go + 9, 64);
    const float P41q = __shfl(PUq, go + 9, 64);
    const float vs0  = __shfl(vsk, go + 0, 64);
    const float vs8  = __shfl(vsk, go + 8, 64);
    const float r0   = __shfl(e0, go + 0, 64);
    const float r62  = __shfl(e2, go + 15, 64);   // t0=60 -> e2 = r[62]
    const float r42  = __shfl(e2, go + 10, 64);   // t0=40 -> e2 = r[42]

    // ---- scalar features (computed in all lanes of the group) ----
    const float vol_long  = sqrtf(fmaxf((Q - S * S / 63.f) / 62.f, 0.f));
    const float Ss = S - P41r, Qs = Q - P41q;
    const float vol_short = sqrtf(fmaxf((Qs - Ss * Ss / 21.f) / 20.f, 0.f));

    const float vmean = vsum / 9.f;
    const float vol_persistence = sqrtf(fmaxf(vsqs / 9.f - vmean * vmean, 0.f));
    const float vol_trend = vs0 - vs8;

    const float Sa = S - r62, Sb = S - r0;
    const float Qa = Q - r62 * r62, Qb = Q - r0 * r0;
    const float num = SL - Sa * Sb / 62.f;
    const float va = Qa - Sa * Sa / 62.f;
    const float vb = Qb - Sb * Sb / 62.f;
    const float corr = num / sqrtf(va * vb);
    const float trend = (corr != corr) ? 0.5f : fabsf(corr);

    const float mean_returns = S / 63.f;
    const float abs_mean = SA / 63.f;
    const float range = MX - MN;
    float skew = 0.f;
    if (vol_long >= 1e-8f) {
        const float mu = mean_returns;
        const float cs = SC - 3.f * mu * Q + 2.f * 63.f * mu * mu * mu;
        skew = cs / (63.f * vol_long * vol_long * vol_long);
    }
    const float momentum_short = r62 / (r42 + 1e-8f) - 1.f;
    const float vol_ratio = vol_short / (vol_long + 1e-8f);
    const float high_vol = (vol_short > 0.03f) ? 1.f : 0.f;
    const float med_vol  = (vol_short >= 0.01f && vol_short <= 0.03f) ? 1.f : 0.f;
    const float low_vol  = (vol_short < 0.01f) ? 1.f : 0.f;
    const float vol_feature_mean = SV / 21.f;

    // ---- write: lane li writes feature li, and feature li+16 if li<5 ----
    float f;
    switch (li) {
        case 0:  f = high_vol; break;
        case 1:  f = med_vol; break;
        case 2:  f = low_vol; break;
        case 3:  f = trend; break;
        case 4:  f = vol_ratio; break;
        case 5:  f = mean_returns; break;
        case 6:  f = abs_mean; break;
        case 7:  f = range; break;
        case 8:  f = skew; break;
        case 9:  f = momentum_short; break;
        case 10: f = rsi_c; break;
        case 11: f = vol_feature_mean; break;
        case 12: f = momf_c; break;
        case 13: f = 0.f; break;   // relative_return
        case 14: f = 1.f; break;   // relative_vol
        default: f = 1.f; break;   // beta (li==15)
    }
    out[(size_t)row * 21 + li] = f;

    if (li < 5) {
        float g;
        switch (li) {
            case 0:  g = 0.f; break;              // relative_strength
            case 1:  g = 0.02f; break;            // market_vol_level
            case 2:  g = vol_persistence; break;
            case 3:  g = vol_trend; break;
            default: g = 0.f; break;              // regime_shift
        }
        out[(size_t)row * 21 + 16 + li] = g;
    }
}

extern "C" void kernel_launch(void* const* d_in, const int* in_sizes, int n_in,
                              void* d_out, int out_size, void* d_ws, size_t ws_size,
                              hipStream_t stream) {
    const float* x = (const float*)d_in[0];
    float* out = (float*)d_out;
    const int B = in_sizes[0] / (63 * 16);
    const int blocks = (B + 15) / 16;   // 16 rows per block (4 waves x 4 rows)
    regime_kernel<<<blocks, 256, 0, stream>>>(x, out, B);
}